// Round 9
// baseline (333.835 us; speedup 1.0000x reference)
//
#include <hip/hip_runtime.h>
#include <math.h>

#define BSZ   2048
#define INDIM 1024
#define QDIM  2048   // HEADS*K_DIM
#define NHT   8      // HEADS*2
#define NKEYS 512
#define HALFD 256
#define KNN   32
#define VDIM  1024
#define HEADS 4

typedef _Float16 v8h __attribute__((ext_vector_type(8)));
typedef _Float16 v4h __attribute__((ext_vector_type(4)));
typedef float    v4f __attribute__((ext_vector_type(4)));

// ---------- f32 -> {h, h/64, m=64*(a-h)} f16 plane split ----------
// A-side plane order: [h, h/64, m]; B-side: [h, m, h/64]
template<int KSHIFT, bool ASIDE>
__device__ __forceinline__ void split4(const float* __restrict__ in,
                                       _Float16* __restrict__ out, int i) {
  const long e0 = (long)i * 4;
  const int K = 1 << KSHIFT;
  const long r = e0 >> KSHIFT;
  const int k = (int)(e0 & (K - 1));
  const float4 a = *(const float4*)&in[e0];
  const float av[4] = {a.x, a.y, a.z, a.w};
  v4h hv, dv, mv;
  #pragma unroll
  for (int u = 0; u < 4; ++u) {
    const _Float16 hh = (_Float16)av[u];
    hv[u] = hh;
    mv[u] = (_Float16)((av[u] - (float)hh) * 64.0f);
    dv[u] = (_Float16)((float)hh * 0.015625f);
  }
  _Float16* base = out + r * (3L * K) + k;
  *(v4h*)(base)         = hv;
  *(v4h*)(base + K)     = ASIDE ? dv : mv;
  *(v4h*)(base + 2 * K) = ASIDE ? mv : dv;
}

__global__ __launch_bounds__(256) void split_all_kernel(
    const float* __restrict__ x, const float* __restrict__ wq, const float* __restrict__ ky,
    _Float16* __restrict__ xs, _Float16* __restrict__ wqs, _Float16* __restrict__ kys) {
  const int i = blockIdx.x * 256 + threadIdx.x;
  if (i < 524288)            split4<10, true >(x,  xs,  i);
  else if (i < 1048576)      split4<10, false>(wq, wqs, i - 524288);
  else                       split4<8,  false>(ky, kys, i - 1048576);
}

// ---------- async global->LDS 16B ----------
__device__ __forceinline__ void gload16(const _Float16* g, _Float16* l) {
  __builtin_amdgcn_global_load_lds(
      (const __attribute__((address_space(1))) unsigned int*)g,
      (__attribute__((address_space(3))) unsigned int*)l, 16, 0, 0);
}

#define WAITV16 asm volatile("s_waitcnt vmcnt(16)" ::: "memory")
#define WAITV8  asm volatile("s_waitcnt vmcnt(8)" ::: "memory")
#define WAITV4  asm volatile("s_waitcnt vmcnt(4)" ::: "memory")
#define WAITV0  asm volatile("s_waitcnt vmcnt(0)" ::: "memory")

// =================== GEMM1: Q'' = split(xs @ wqs^T + b) ===================
// 128x128 tile, BK=64, 4-buffer 3-ahead counted-vmcnt pipeline, 128 KB LDS.
// Staging swizzle (R5-verified): byte ^= ((byte>>7)&7)<<4 within [row][128B].
__global__ __launch_bounds__(256) void gemm1_kernel(
    const _Float16* __restrict__ A, const _Float16* __restrict__ B,
    const float* __restrict__ bias, _Float16* __restrict__ Cq) {
  __shared__ __align__(16) char smem[131072];   // 4 bufs x (A 16KB + B 16KB)
  _Float16* sh = (_Float16*)smem;
  const int t = threadIdx.x;
  const int m0 = blockIdx.y * 128, n0 = blockIdx.x * 128;
  const int lane = t & 63, w = t >> 6;
  const int wr = (w >> 1) * 64, wc = (w & 1) * 64;
  const int fr = lane & 15, kg = lane >> 4;

  const _Float16* gA[4]; const _Float16* gB[4];
  int dA[4], dB[4];
  #pragma unroll
  for (int p = 0; p < 4; ++p) {
    const int O = p * 4096 + t * 16;
    const int os = O ^ (((O >> 7) & 7) << 4);
    const int srow = os >> 7, sk = (os & 127) >> 1;
    gA[p] = A + (size_t)(m0 + srow) * 3072 + sk;
    gB[p] = B + (size_t)(n0 + srow) * 3072 + sk;
    dA[p] = O >> 1;
    dB[p] = (16384 + O) >> 1;
  }

  int aof[2][4], bof[2][4];
  #pragma unroll
  for (int ks = 0; ks < 2; ++ks)
    #pragma unroll
    for (int i = 0; i < 4; ++i) {
      const int ra = wr + i * 16 + fr;
      aof[ks][i] = (ra * 128 + ((((ks << 2) | kg) ^ (fr & 7)) << 4)) >> 1;
      const int rb = wc + i * 16 + fr;
      bof[ks][i] = ((rb * 128 + ((((ks << 2) | kg) ^ (fr & 7)) << 4)) >> 1) + 8192;
    }

  v4f acc[4][4];
  #pragma unroll
  for (int i = 0; i < 4; ++i)
    #pragma unroll
    for (int j = 0; j < 4; ++j)
      acc[i][j] = (v4f){0.f, 0.f, 0.f, 0.f};

  const int nt = 48;   // 3072 / 64

  // prologue: stage tiles 0..2 into bufs 0..2 (24 loads in flight)
  #pragma unroll
  for (int p2 = 0; p2 < 3; ++p2) {
    _Float16* bb = sh + p2 * 16384;
    const size_t ko = (size_t)p2 * 64;
    #pragma unroll
    for (int p = 0; p < 4; ++p) {
      gload16(gA[p] + ko, bb + dA[p]);
      gload16(gB[p] + ko, bb + dB[p]);
    }
  }
  WAITV16;                             // tile 0 landed
  __builtin_amdgcn_s_barrier();
  __builtin_amdgcn_sched_barrier(0);

  for (int tt = 0; tt < nt; ++tt) {
    const _Float16* bb = sh + (tt & 3) * 16384;
    if (tt + 3 < nt) {
      _Float16* nb = sh + ((tt + 3) & 3) * 16384;
      const size_t ko = (size_t)(tt + 3) * 64;
      #pragma unroll
      for (int p = 0; p < 4; ++p) {
        gload16(gA[p] + ko, nb + dA[p]);
        gload16(gB[p] + ko, nb + dB[p]);
      }
    }
    #pragma unroll
    for (int ks = 0; ks < 2; ++ks) {
      v8h af[4], bf[4];
      #pragma unroll
      for (int i = 0; i < 4; ++i) af[i] = *(const v8h*)(bb + aof[ks][i]);
      #pragma unroll
      for (int j = 0; j < 4; ++j) bf[j] = *(const v8h*)(bb + bof[ks][j]);
      #pragma unroll
      for (int i = 0; i < 4; ++i)
        #pragma unroll
        for (int j = 0; j < 4; ++j)
          acc[i][j] = __builtin_amdgcn_mfma_f32_16x16x32_f16(af[i], bf[j], acc[i][j], 0, 0, 0);
    }
    if (tt + 3 < nt)      { WAITV16; }
    else if (tt + 2 < nt) { WAITV8; }
    else if (tt + 1 < nt) { WAITV0; }
    __builtin_amdgcn_s_barrier();
    __builtin_amdgcn_sched_barrier(0);
  }

  // epilogue: bias + 3-plane f16 split via LDS transpose (two 64-col halves)
  float* Ct = (float*)smem;
  #pragma unroll
  for (int half = 0; half < 2; ++half) {
    __syncthreads();
    if ((w & 1) == half) {
      #pragma unroll
      for (int j = 0; j < 4; ++j) {
        const int colq = j * 16 + fr;
        const float bv = bias[n0 + half * 64 + colq];
        #pragma unroll
        for (int i = 0; i < 4; ++i)
          #pragma unroll
          for (int rr = 0; rr < 4; ++rr)
            Ct[(wr + i * 16 + kg * 4 + rr) * 68 + colq] = acc[i][j][rr] + bv;
      }
    }
    __syncthreads();
    const int r = t >> 1, cb = (t & 1) * 32;
    const int gcol = n0 + half * 64 + cb;
    const int ht = gcol >> 8, dd = gcol & 255;
    _Float16* p = Cq + (size_t)(m0 + r) * (3 * HALFD * NHT) + ht * (3 * HALFD) + dd;
    #pragma unroll
    for (int u = 0; u < 32; u += 8) {
      float vv[8];
      *(float4*)&vv[0] = *(const float4*)&Ct[r * 68 + cb + u];
      *(float4*)&vv[4] = *(const float4*)&Ct[r * 68 + cb + u + 4];
      v8h hv, dv, mv;
      #pragma unroll
      for (int e = 0; e < 8; ++e) {
        const _Float16 hh = (_Float16)vv[e];
        hv[e] = hh;
        mv[e] = (_Float16)((vv[e] - (float)hh) * 64.0f);
        dv[e] = (_Float16)((float)hh * 0.015625f);
      }
      *(v8h*)(p + u) = hv;
      *(v8h*)(p + HALFD + u) = dv;
      *(v8h*)(p + 2 * HALFD + u) = mv;
    }
  }
}

// =================== GEMM2: S = Q'' @ keys''^T (R7-proven, BK=32) ===================
__global__ __launch_bounds__(256) void gemm2_kernel(
    const _Float16* __restrict__ A, int lda, long aBS,
    const _Float16* __restrict__ B, int ldb, long bBS,
    float* __restrict__ Cf, int ldc, long cBS, int K) {
  __shared__ __align__(16) char smem[65536];   // 4 bufs x (A 8KB + B 8KB)
  _Float16* sh = (_Float16*)smem;
  const int t = threadIdx.x;
  const int z = blockIdx.z;
  const _Float16* Ab = A + (size_t)z * aBS;
  const _Float16* Bb = B + (size_t)z * bBS;
  const int m0 = blockIdx.y * 128, n0 = blockIdx.x * 128;

  const int o0 = t * 16;
  const int os = o0 ^ (((o0 >> 7) & 3) << 4);
  const int sr = os >> 6;
  const int sk = (os & 63) >> 1;
  const _Float16* gA0 = Ab + (size_t)(m0 + sr) * lda + sk;
  const _Float16* gA1 = Ab + (size_t)(m0 + sr + 64) * lda + sk;
  const _Float16* gB0 = Bb + (size_t)(n0 + sr) * ldb + sk;
  const _Float16* gB1 = Bb + (size_t)(n0 + sr + 64) * ldb + sk;
  const int t8 = t * 8;

  const int lane = t & 63, w = t >> 6;
  const int wr = (w >> 1) * 64, wc = (w & 1) * 64;
  const int fr = lane & 15, kg = lane >> 4;

  int aoff[4], boff[4];
  #pragma unroll
  for (int i = 0; i < 4; ++i) {
    const int ra = wr + i * 16 + fr;
    aoff[i] = (ra * 64 + ((kg ^ ((ra >> 1) & 3)) * 16)) >> 1;
    const int rb = wc + i * 16 + fr;
    boff[i] = ((rb * 64 + ((kg ^ ((rb >> 1) & 3)) * 16)) >> 1) + 4096;
  }

  v4f acc[4][4];
  #pragma unroll
  for (int i = 0; i < 4; ++i)
    #pragma unroll
    for (int j = 0; j < 4; ++j)
      acc[i][j] = (v4f){0.f, 0.f, 0.f, 0.f};

  const int nt = K >> 5;

  #pragma unroll
  for (int p = 0; p < 3; ++p) {
    _Float16* bb = sh + p * 8192;
    const size_t ko = (size_t)p * 32;
    gload16(gA0 + ko, bb + t8);
    gload16(gA1 + ko, bb + 2048 + t8);
    gload16(gB0 + ko, bb + 4096 + t8);
    gload16(gB1 + ko, bb + 6144 + t8);
  }
  WAITV8;
  __builtin_amdgcn_s_barrier();
  __builtin_amdgcn_sched_barrier(0);

  for (int tt = 0; tt < nt; ++tt) {
    const _Float16* bb = sh + (tt & 3) * 8192;
    if (tt + 3 < nt) {
      _Float16* nb = sh + ((tt + 3) & 3) * 8192;
      const size_t ko = (size_t)(tt + 3) * 32;
      gload16(gA0 + ko, nb + t8);
      gload16(gA1 + ko, nb + 2048 + t8);
      gload16(gB0 + ko, nb + 4096 + t8);
      gload16(gB1 + ko, nb + 6144 + t8);
    }
    v8h af[4], bf[4];
    #pragma unroll
    for (int i = 0; i < 4; ++i) af[i] = *(const v8h*)(bb + aoff[i]);
    #pragma unroll
    for (int j = 0; j < 4; ++j) bf[j] = *(const v8h*)(bb + boff[j]);
    #pragma unroll
    for (int i = 0; i < 4; ++i)
      #pragma unroll
      for (int j = 0; j < 4; ++j)
        acc[i][j] = __builtin_amdgcn_mfma_f32_16x16x32_f16(af[i], bf[j], acc[i][j], 0, 0, 0);
    if (tt + 3 < nt)      { WAITV8; }
    else if (tt + 2 < nt) { WAITV4; }
    else if (tt + 1 < nt) { WAITV0; }
    __builtin_amdgcn_s_barrier();
    __builtin_amdgcn_sched_barrier(0);
  }

  float* Cb = Cf + (size_t)z * cBS;
  #pragma unroll
  for (int i = 0; i < 4; ++i)
    #pragma unroll
    for (int j = 0; j < 4; ++j)
      #pragma unroll
      for (int rr = 0; rr < 4; ++rr) {
        const int rowg = m0 + wr + i * 16 + kg * 4 + rr;
        const int colg = n0 + wc + j * 16 + fr;
        Cb[(size_t)rowg * ldc + colg] = acc[i][j][rr];
      }
}

// ====== topk1 (x2) + cartesian-topk2 with FUSED gather, one block/token ======
// Wave h owns head h. out = (sum_k e_k * values[row_k]) * (1/Z): each cartesian
// round issues its row's loads; FMA of previous row hides under next round's
// shuffle chain. Selection order / tie rules identical to R8.
__global__ __launch_bounds__(256) void topk_all_gather_kernel(
    const float* __restrict__ S, const float* __restrict__ values,
    float* __restrict__ out) {
  __shared__ float ls1[4][32], ls2[4][32];
  __shared__ int   li1[4][32], li2[4][32];
  __shared__ float red[4][1024];   // per-wave partial outputs (16 KB)
  const int b = blockIdx.x, t = threadIdx.x;
  const int lane = t & 63, h = t >> 6;
  const float* srA = S + ((size_t)b * NHT + 2 * h) * NKEYS;
  const float* srB = srA + NKEYS;
  float va[8], vb[8];
  #pragma unroll
  for (int j = 0; j < 8; ++j) va[j] = srA[j * 64 + lane];
  #pragma unroll
  for (int j = 0; j < 8; ++j) vb[j] = srB[j * 64 + lane];

  // ---- top-32 of row A (ht=2h) ----
  for (int r = 0; r < KNN; ++r) {
    float bv = -INFINITY; int bi = 0x7fffffff;
    #pragma unroll
    for (int j = 0; j < 8; ++j) {
      const int idx = j * 64 + lane;
      if (va[j] > bv) { bv = va[j]; bi = idx; }
    }
    #pragma unroll
    for (int off = 32; off > 0; off >>= 1) {
      const float ov = __shfl_xor(bv, off);
      const int oi = __shfl_xor(bi, off);
      if (ov > bv || (ov == bv && oi < bi)) { bv = ov; bi = oi; }
    }
    if (lane == 0) { ls1[h][r] = bv; li1[h][r] = bi; }
    const int jj = bi >> 6;
    const bool mine = (bi & 63) == lane;
    #pragma unroll
    for (int j = 0; j < 8; ++j)
      if (mine && j == jj) va[j] = -INFINITY;
  }
  // ---- top-32 of row B (ht=2h+1) ----
  for (int r = 0; r < KNN; ++r) {
    float bv = -INFINITY; int bi = 0x7fffffff;
    #pragma unroll
    for (int j = 0; j < 8; ++j) {
      const int idx = j * 64 + lane;
      if (vb[j] > bv) { bv = vb[j]; bi = idx; }
    }
    #pragma unroll
    for (int off = 32; off > 0; off >>= 1) {
      const float ov = __shfl_xor(bv, off);
      const int oi = __shfl_xor(bi, off);
      if (ov > bv || (ov == bv && oi < bi)) { bv = ov; bi = oi; }
    }
    if (lane == 0) { ls2[h][r] = bv; li2[h][r] = bi; }
    const int jj = bi >> 6;
    const bool mine = (bi & 63) == lane;
    #pragma unroll
    for (int j = 0; j < 8; ++j)
      if (mine && j == jj) vb[j] = -INFINITY;
  }

  // ---- cartesian top-32 with fused weighted gather ----
  float v[16];
  #pragma unroll
  for (int c = 0; c < 16; ++c) {
    const int p = c * 64 + lane;
    v[c] = ls1[h][p >> 5] + ls2[h][p & 31];
  }
  float4 acc0 = {0,0,0,0}, acc1 = {0,0,0,0}, acc2 = {0,0,0,0}, acc3 = {0,0,0,0};
  float4 pv0, pv1, pv2, pv3;
  float pe = 0.0f, m = 0.0f, Z = 0.0f;
  for (int r = 0; r < KNN; ++r) {
    float bv = -INFINITY; int bp = 0x7fffffff;
    #pragma unroll
    for (int c = 0; c < 16; ++c) {
      const int p = c * 64 + lane;
      if (v[c] > bv) { bv = v[c]; bp = p; }
    }
    #pragma unroll
    for (int off = 32; off > 0; off >>= 1) {
      const float ov = __shfl_xor(bv, off);
      const int op = __shfl_xor(bp, off);
      if (ov > bv || (ov == bv && op < bp)) { bv = ov; bp = op; }
    }
    // all lanes agree on (bv, bp)
    const int row = li1[h][bp >> 5] * NKEYS + li2[h][bp & 31];
    if (r == 0) m = bv;
    const float e = expf(bv - m);
    Z += e;
    // issue this row's loads (4 x dwordx4 per lane; wave covers full 4 KB row)
    const float4* vp = (const float4*)(values + (size_t)row * VDIM) + lane;
    const float4 c0 = vp[0], c1 = vp[64], c2 = vp[128], c3 = vp[192];
    // accumulate PREVIOUS row (overlaps with this round's loads in flight)
    if (r > 0) {
      acc0.x = fmaf(pe, pv0.x, acc0.x); acc0.y = fmaf(pe, pv0.y, acc0.y);
      acc0.z = fmaf(pe, pv0.z, acc0.z); acc0.w = fmaf(pe, pv0.w, acc0.w);
      acc1.x = fmaf(pe, pv1.x, acc1.x); acc1.y = fmaf(pe, pv1.y, acc1.y);
      acc1.z = fmaf(pe, pv1.z, acc1.z); acc1.w = fmaf(pe, pv1.w, acc1.w);
      acc2.x = fmaf(pe, pv2.x, acc2.x); acc2.y = fmaf(pe, pv2.y, acc2.y);
      acc2.z = fmaf(pe, pv2.z, acc2.z); acc2.w = fmaf(pe, pv2.w, acc2.w);
      acc3.x = fmaf(pe, pv3.x, acc3.x); acc3.y = fmaf(pe, pv3.y, acc3.y);
      acc3.z = fmaf(pe, pv3.z, acc3.z); acc3.w = fmaf(pe, pv3.w, acc3.w);
    }
    pv0 = c0; pv1 = c1; pv2 = c2; pv3 = c3; pe = e;
    // removal
    const int cc = bp >> 6;
    const bool mine = (bp & 63) == lane;
    #pragma unroll
    for (int c = 0; c < 16; ++c)
      if (mine && c == cc) v[c] = -INFINITY;
  }
  // final pending row + normalize
  const float invZ = 1.0f / Z;
  acc0.x = fmaf(pe, pv0.x, acc0.x); acc0.y = fmaf(pe, pv0.y, acc0.y);
  acc0.z = fmaf(pe, pv0.z, acc0.z); acc0.w = fmaf(pe, pv0.w, acc0.w);
  acc1.x = fmaf(pe, pv1.x, acc1.x); acc1.y = fmaf(pe, pv1.y, acc1.y);
  acc1.z = fmaf(pe, pv1.z, acc1.z); acc1.w = fmaf(pe, pv1.w, acc1.w);
  acc2.x = fmaf(pe, pv2.x, acc2.x); acc2.y = fmaf(pe, pv2.y, acc2.y);
  acc2.z = fmaf(pe, pv2.z, acc2.z); acc2.w = fmaf(pe, pv2.w, acc2.w);
  acc3.x = fmaf(pe, pv3.x, acc3.x); acc3.y = fmaf(pe, pv3.y, acc3.y);
  acc3.z = fmaf(pe, pv3.z, acc3.z); acc3.w = fmaf(pe, pv3.w, acc3.w);
  acc0.x *= invZ; acc0.y *= invZ; acc0.z *= invZ; acc0.w *= invZ;
  acc1.x *= invZ; acc1.y *= invZ; acc1.z *= invZ; acc1.w *= invZ;
  acc2.x *= invZ; acc2.y *= invZ; acc2.z *= invZ; acc2.w *= invZ;
  acc3.x *= invZ; acc3.y *= invZ; acc3.z *= invZ; acc3.w *= invZ;

  float4* rp = (float4*)&red[h][0];
  rp[lane] = acc0; rp[lane + 64] = acc1; rp[lane + 128] = acc2; rp[lane + 192] = acc3;
  __syncthreads();
  const float4* r0 = (const float4*)&red[0][0];
  const float4* r1 = (const float4*)&red[1][0];
  const float4* r2 = (const float4*)&red[2][0];
  const float4* r3 = (const float4*)&red[3][0];
  float4 o;
  o.x = r0[t].x + r1[t].x + r2[t].x + r3[t].x;
  o.y = r0[t].y + r1[t].y + r2[t].y + r3[t].y;
  o.z = r0[t].z + r1[t].z + r2[t].z + r3[t].z;
  o.w = r0[t].w + r1[t].w + r2[t].w + r3[t].w;
  ((float4*)&out[(size_t)b * VDIM])[t] = o;
}

extern "C" void kernel_launch(void* const* d_in, const int* in_sizes, int n_in,
                              void* d_out, int out_size, void* d_ws, size_t ws_size,
                              hipStream_t stream) {
  const float* x      = (const float*)d_in[0];
  const float* w_q    = (const float*)d_in[1];
  const float* b_q    = (const float*)d_in[2];
  const float* keys   = (const float*)d_in[3];
  const float* values = (const float*)d_in[4];
  float* out = (float*)d_out;

  char* ws = (char*)d_ws;
  _Float16* xs    = (_Float16*)(ws);                  // 2048*3072*2 = 12.6 MB
  _Float16* wqs   = (_Float16*)(ws + (16u  << 20));   // 12.6 MB
  _Float16* keyss = (_Float16*)(ws + (32u  << 20));   // 4096*768*2 = 6.3 MB
  _Float16* Qs    = (_Float16*)(ws + (40u  << 20));   // 2048*6144*2 = 25.2 MB
  float*    S     = (float*)   (ws + (68u  << 20));   // 2048*4096*4 = 32 MB

  split_all_kernel<<<5120, 256, 0, stream>>>(x, w_q, keys, xs, wqs, keyss);

  // GEMM1: M=2048, N=2048, K'=3072 (BK=64 pipeline)
  gemm1_kernel<<<dim3(QDIM / 128, BSZ / 128), 256, 0, stream>>>(xs, wqs, b_q, Qs);
  // GEMM2: 8 x (M=2048, N=512, K'=768) (BK=32 pipeline, 2 blocks/CU)
  gemm2_kernel<<<dim3(NKEYS / 128, BSZ / 128, NHT), 256, 0, stream>>>(
      Qs, 3 * HALFD * NHT, 3 * HALFD, keyss, 3 * HALFD, (long)NKEYS * 3 * HALFD,
      S, NHT * NKEYS, NKEYS, 3 * HALFD);

  topk_all_gather_kernel<<<BSZ, 256, 0, stream>>>(S, values, out);
}